// Round 8
// baseline (278.947 us; speedup 1.0000x reference)
//
#include <hip/hip_runtime.h>
#include <hip/hip_bf16.h>
#include <math.h>

#define Bn 8
#define Tn 2048
#define Cn 1024
#define Hn 64
#define BTHb ((size_t)Bn * Tn * Hn)   // elements per projected matrix (bf16)
#define WLU  8192                     // 16B W-fragment units per matrix
#define WLS  ((size_t)WLU * 8)        // shorts per matrix (128 KB)

typedef __attribute__((ext_vector_type(8))) short bf16x8;
typedef __attribute__((ext_vector_type(4))) float f32x4;

static __device__ __forceinline__ unsigned short bf16rne(float f) {
    union { float f; unsigned u; } x; x.f = f;
    return (unsigned short)((x.u + 0x7FFFu + ((x.u >> 16) & 1u)) >> 16);
}

// HW round-to-nearest-even f32->bf16 (pairs into v_cvt_pk_bf16_f32)
static __device__ __forceinline__ unsigned short hwbf16(float f) {
    union { __hip_bfloat16 h; unsigned short u; } c;
    c.h = __float2bfloat16(f);
    return c.u;
}

static __device__ __forceinline__ bf16x8 cvt8(const float4 a, const float4 b) {
    bf16x8 r;
    r[0] = (short)hwbf16(a.x); r[1] = (short)hwbf16(a.y);
    r[2] = (short)hwbf16(a.z); r[3] = (short)hwbf16(a.w);
    r[4] = (short)hwbf16(b.x); r[5] = (short)hwbf16(b.y);
    r[6] = (short)hwbf16(b.z); r[7] = (short)hwbf16(b.w);
    return r;
}

// ---------------------------------------------------------------------------
// W pre-conversion: fp32 W[h][c] -> bf16 MFMA B-fragments, fragment-ordered.
// Output parked in d_out (384 KB of 4 MB; attn fully overwrites out after).
// ---------------------------------------------------------------------------
__global__ __launch_bounds__(256) void wconv_kernel(
    const float* __restrict__ Wk, const float* __restrict__ Wq,
    const float* __restrict__ Wv, unsigned short* __restrict__ WL)
{
    const int which = blockIdx.y;
    const float* W = (which == 0) ? Wk : (which == 1) ? Wq : Wv;
    unsigned short* dst = WL + (size_t)which * WLS;
    const int tid = threadIdx.x;
#pragma unroll
    for (int i = 0; i < 4; ++i) {
        const int u    = blockIdx.x * 1024 + i * 256 + tid;
        const int kc32 = u >> 8;
        const int ht   = (u >> 6) & 3;
        const int l    = u & 63;
        const float* wp =
            W + (size_t)(ht * 16 + (l & 15)) * Cn + kc32 * 32 + (l >> 4) * 8;
        const float4 a = *(const float4*)wp;
        const float4 b = *(const float4*)(wp + 4);
        *(bf16x8*)&dst[(size_t)u * 8] = cvt8(a, b);
    }
}

// ---------------------------------------------------------------------------
// MFMA projection (v8 structure, kept): sequential staged reads -> swizzled
// LDS bf16 tile -> K-split x4 MFMA -> LDS reduce. ~82us; proj has resisted
// 8 structural attacks all pinned at ~1.3 TB/s HBM -- treated as plateau.
// ---------------------------------------------------------------------------
__global__ __launch_bounds__(256, 4) void proj_kernel(
    const float* __restrict__ k, const float* __restrict__ q,
    const float* __restrict__ v,
    const unsigned short* __restrict__ WL,
    unsigned short* __restrict__ ws)
{
    const int which = blockIdx.y;
    const float* X = (which == 0) ? k : (which == 1) ? q : v;
    const unsigned short* WLm = WL + (size_t)which * WLS;
    unsigned short* O = ws + (size_t)which * BTHb;

    __shared__ __align__(16) float smem[8192];          // 32 KB
    unsigned short* Xbf = (unsigned short*)smem;        // [16][1024] swizzled

    const int tid  = threadIdx.x;
    const int wave = __builtin_amdgcn_readfirstlane(tid >> 6);  // K-quarter
    const int lane = tid & 63;
    const int m    = lane & 15;
    const int quad = lane >> 4;
    const int row0 = blockIdx.x * 16;

    const float* Xt = X + (size_t)row0 * Cn + tid * 4;
#pragma unroll
    for (int p = 0; p < 16; ++p) {
        const float4 xv = *(const float4*)(Xt + (size_t)p * Cn);
        ushort4 xb;
        xb.x = hwbf16(xv.x); xb.y = hwbf16(xv.y);
        xb.z = hwbf16(xv.z); xb.w = hwbf16(xv.w);
        const int pu = (tid >> 1) ^ (p & 7);   // 16B-unit XOR swizzle
        *(ushort4*)&Xbf[p * 1024 + pu * 8 + (tid & 1) * 4] = xb;
    }
    __syncthreads();

    f32x4 acc[4];
#pragma unroll
    for (int t = 0; t < 4; ++t) acc[t] = (f32x4){0.f, 0.f, 0.f, 0.f};

#pragma unroll
    for (int cc = 0; cc < 8; ++cc) {
        const int c  = wave * 8 + cc;
        const int pu = (c * 4 + quad) ^ (m & 7);
        const bf16x8 a = *(const bf16x8*)&Xbf[m * 1024 + pu * 8];
#pragma unroll
        for (int ht = 0; ht < 4; ++ht) {
            const bf16x8 bfr =
                *(const bf16x8*)&WLm[(size_t)((c * 4 + ht) * 64 + lane) * 8];
            acc[ht] = __builtin_amdgcn_mfma_f32_16x16x32_bf16(
                a, bfr, acc[ht], 0, 0, 0);
        }
    }

    __syncthreads();   // everyone done reading Xbf
    float (*Rs)[64][17] = (float (*)[64][17])smem;      // 13 KB < 32 KB
    if (wave > 0) {
#pragma unroll
        for (int ht = 0; ht < 4; ++ht)
#pragma unroll
            for (int r = 0; r < 4; ++r)
                Rs[wave - 1][lane][ht * 4 + r] = acc[ht][r];
    }
    __syncthreads();
    if (wave == 0) {
#pragma unroll
        for (int w = 0; w < 3; ++w)
#pragma unroll
            for (int ht = 0; ht < 4; ++ht)
#pragma unroll
                for (int r = 0; r < 4; ++r)
                    acc[ht][r] += Rs[w][lane][ht * 4 + r];

#pragma unroll
        for (int ht = 0; ht < 4; ++ht)
#pragma unroll
            for (int r = 0; r < 4; ++r)
                O[(size_t)(row0 + quad * 4 + r) * Hn + ht * 16 + m] =
                    bf16rne(acc[ht][r]);
    }
}

// ---------------------------------------------------------------------------
// MFMA flash attention v9: 32-ROW BLOCKS, DEEP-FIRST DISPATCH.
// Old: 256 blocks (64 q-rows, 4 waves) = 1 block/CU; wall = the qt=31
// blocks' SERIAL 32-tile chain (stage->barrier->compute ~6000cy/tile vs
// ~600cy work) with nothing co-resident to hide the stalls.
// New: 512 blocks x 128 thr (2 waves, 16 q-rows each). LDS 23KB -> many
// blocks/CU can co-reside; bx maps deepest chunks first interleaved
// across batches (b = bx&7, chunk j = 63-(bx>>3)) so long chains start
// at t=0 and shallow blocks backfill the CUs. Per-wave pipeline (MFMA
// layouts, K/V register prefetch, online softmax) unchanged; staging
// re-derived for 128 threads (K: 64B/thread; V: 32-short transpose).
// ---------------------------------------------------------------------------
__global__ __launch_bounds__(128, 2) void attn_kernel(
    const unsigned short* __restrict__ ws,
    const int* __restrict__ mask,
    float* __restrict__ out)
{
    const unsigned short* kh = ws;
    const unsigned short* qh = ws + BTHb;
    const unsigned short* vh = ws + 2 * BTHb;

    const int b   = blockIdx.x & 7;            // batch (interleaved)
    const int j   = 63 - (blockIdx.x >> 3);    // 32-row chunk, deep first
    const int tid = threadIdx.x;
    const int wave = __builtin_amdgcn_readfirstlane(tid >> 6);
    const int lane = tid & 63;
    const int ln   = lane & 15;
    const int quad = lane >> 4;

    __shared__ unsigned short Ks[64][72];   // [kpos][dim]
    __shared__ unsigned short Vt[64][72];   // [dim][kpos]
    __shared__ unsigned short Ps[32][72];   // [q-row local][kpos]
    __shared__ int Msk[64];

    const int ntile = (j >> 1) + 1;         // key tiles for this chunk
    const int wrb = j * 32 + wave * 16;     // wave's first q-row

    // Q A-frags: A[m=ln][k=quad*8+jj], 2 chunks of K=32
    bf16x8 qa[2];
#pragma unroll
    for (int kc = 0; kc < 2; ++kc)
        qa[kc] = *(const bf16x8*)(qh + ((size_t)b * Tn + wrb + ln) * Hn
                                     + kc * 32 + quad * 8);

    f32x4 oacc[4];
#pragma unroll
    for (int t = 0; t < 4; ++t) oacc[t] = (f32x4){0.f, 0.f, 0.f, 0.f};
    float mrow[4] = {-1e30f, -1e30f, -1e30f, -1e30f};
    float lrow[4] = {0.f, 0.f, 0.f, 0.f};

    // staging (128 threads): K row=tid>>1, half=tid&1 (64B each);
    //                        V key=tid&63, dims (tid>>6)*32..+32 (transpose)
    const int krow = tid >> 1, kseg = tid & 1;
    const int vcol = tid & 63, vseg = tid >> 6;

    uint4 kreg[4], vreg[4];
    int mreg = 0;
    {
        const unsigned short* kp =
            kh + ((size_t)b * Tn + krow) * Hn + kseg * 32;
        kreg[0] = *(const uint4*)kp;
        kreg[1] = *(const uint4*)(kp + 8);
        kreg[2] = *(const uint4*)(kp + 16);
        kreg[3] = *(const uint4*)(kp + 24);
        const unsigned short* vp =
            vh + ((size_t)b * Tn + vcol) * Hn + vseg * 32;
        vreg[0] = *(const uint4*)vp;
        vreg[1] = *(const uint4*)(vp + 8);
        vreg[2] = *(const uint4*)(vp + 16);
        vreg[3] = *(const uint4*)(vp + 24);
        if (tid < 64) mreg = mask[(size_t)b * Tn + tid];
    }

    for (int jj = 0; jj < ntile; ++jj) {
        __syncthreads();   // previous tile's LDS readers done
        *(uint4*)&Ks[krow][kseg * 32]      = kreg[0];
        *(uint4*)&Ks[krow][kseg * 32 + 8]  = kreg[1];
        *(uint4*)&Ks[krow][kseg * 32 + 16] = kreg[2];
        *(uint4*)&Ks[krow][kseg * 32 + 24] = kreg[3];
        {
            const unsigned short* vs = (const unsigned short*)vreg;
#pragma unroll
            for (int dd = 0; dd < 32; ++dd)
                Vt[vseg * 32 + dd][vcol] = vs[dd];
        }
        if (tid < 64) Msk[tid] = mreg;
        __syncthreads();   // staged tile visible

        if (jj + 1 < ntile) {   // prefetch next tile; overlaps compute
            const unsigned short* kp = kh +
                ((size_t)b * Tn + (jj + 1) * 64 + krow) * Hn + kseg * 32;
            kreg[0] = *(const uint4*)kp;
            kreg[1] = *(const uint4*)(kp + 8);
            kreg[2] = *(const uint4*)(kp + 16);
            kreg[3] = *(const uint4*)(kp + 24);
            const unsigned short* vp = vh +
                ((size_t)b * Tn + (jj + 1) * 64 + vcol) * Hn + vseg * 32;
            vreg[0] = *(const uint4*)vp;
            vreg[1] = *(const uint4*)(vp + 8);
            vreg[2] = *(const uint4*)(vp + 16);
            vreg[3] = *(const uint4*)(vp + 24);
            if (tid < 64) mreg = mask[(size_t)b * Tn + (jj + 1) * 64 + tid];
        }

        // ---- S = Q K^T : 4 col-tiles (16 kpos each) x 2 K-chunks ----
        f32x4 sacc[4];
#pragma unroll
        for (int t = 0; t < 4; ++t) sacc[t] = (f32x4){0.f, 0.f, 0.f, 0.f};
#pragma unroll
        for (int kc = 0; kc < 2; ++kc) {
#pragma unroll
            for (int nt = 0; nt < 4; ++nt) {
                const bf16x8 kb =
                    *(const bf16x8*)&Ks[nt * 16 + ln][kc * 32 + quad * 8];
                sacc[nt] = __builtin_amdgcn_mfma_f32_16x16x32_bf16(
                    qa[kc], kb, sacc[nt], 0, 0, 0);
            }
        }

        // ---- online softmax in C-layout (rows quad*4+r, col nt*16+ln) ----
        const bool fullv = (64 * (jj + 1) <= 32 * j);  // tile fully valid
        float pv[4][4];
        float mt[4] = {-1e30f, -1e30f, -1e30f, -1e30f};
#pragma unroll
        for (int nt = 0; nt < 4; ++nt) {
            const bool mk = (Msk[nt * 16 + ln] != 0);
            const int kpos = jj * 64 + nt * 16 + ln;
#pragma unroll
            for (int r = 0; r < 4; ++r) {
                float s = sacc[nt][r] * 0.125f;
                const bool valid =
                    mk && (fullv || kpos <= wrb + quad * 4 + r);
                s = valid ? s : -1e30f;
                pv[nt][r] = s;
                mt[r] = fmaxf(mt[r], s);
            }
        }
#pragma unroll
        for (int r = 0; r < 4; ++r) {
            mt[r] = fmaxf(mt[r], __shfl_xor(mt[r], 1));
            mt[r] = fmaxf(mt[r], __shfl_xor(mt[r], 2));
            mt[r] = fmaxf(mt[r], __shfl_xor(mt[r], 4));
            mt[r] = fmaxf(mt[r], __shfl_xor(mt[r], 8));
        }
        float alpha[4], rsum[4];
#pragma unroll
        for (int r = 0; r < 4; ++r) {
            const float mn = fmaxf(mrow[r], mt[r]);
            alpha[r] = __expf(mrow[r] - mn);
            mrow[r] = mn;
            rsum[r] = 0.f;
        }
#pragma unroll
        for (int nt = 0; nt < 4; ++nt)
#pragma unroll
            for (int r = 0; r < 4; ++r) {
                const float p = (pv[nt][r] <= -1e29f)
                                    ? 0.f
                                    : __expf(pv[nt][r] - mrow[r]);
                pv[nt][r] = p;
                rsum[r] += p;
            }
#pragma unroll
        for (int r = 0; r < 4; ++r) {
            rsum[r] += __shfl_xor(rsum[r], 1);
            rsum[r] += __shfl_xor(rsum[r], 2);
            rsum[r] += __shfl_xor(rsum[r], 4);
            rsum[r] += __shfl_xor(rsum[r], 8);
            lrow[r] = lrow[r] * alpha[r] + rsum[r];
        }
#pragma unroll
        for (int nt = 0; nt < 4; ++nt)
#pragma unroll
            for (int r = 0; r < 4; ++r) oacc[nt][r] *= alpha[r];

        // ---- P -> LDS (bf16), wave-private region ----
#pragma unroll
        for (int nt = 0; nt < 4; ++nt)
#pragma unroll
            for (int r = 0; r < 4; ++r)
                Ps[wave * 16 + quad * 4 + r][nt * 16 + ln] =
                    bf16rne(pv[nt][r]);
        // wave-private LDS round-trip: drain DS writes, keep vmcnt in flight
        asm volatile("s_waitcnt lgkmcnt(0)" ::: "memory");

        // ---- O += P V : A=P[m=ln][k], B=V^T[n=dim][k] ----
#pragma unroll
        for (int kc = 0; kc < 2; ++kc) {
            const bf16x8 pa =
                *(const bf16x8*)&Ps[wave * 16 + ln][kc * 32 + quad * 8];
#pragma unroll
            for (int nt = 0; nt < 4; ++nt) {
                const bf16x8 vb =
                    *(const bf16x8*)&Vt[nt * 16 + ln][kc * 32 + quad * 8];
                oacc[nt] = __builtin_amdgcn_mfma_f32_16x16x32_bf16(
                    pa, vb, oacc[nt], 0, 0, 0);
            }
        }
    }

    // ---- epilogue: divide by l, fp32 store ----
#pragma unroll
    for (int r = 0; r < 4; ++r) {
        const float inv = 1.0f / lrow[r];
        const size_t rowoff = ((size_t)b * Tn + wrb + quad * 4 + r) * Hn;
#pragma unroll
        for (int nt = 0; nt < 4; ++nt)
            out[rowoff + nt * 16 + ln] = oacc[nt][r] * inv;
    }
}

extern "C" void kernel_launch(void* const* d_in, const int* in_sizes, int n_in,
                              void* d_out, int out_size, void* d_ws, size_t ws_size,
                              hipStream_t stream)
{
    const float* k    = (const float*)d_in[0];
    const float* q    = (const float*)d_in[1];
    const float* v    = (const float*)d_in[2];
    const int*   mask = (const int*)d_in[3];
    const float* Wk   = (const float*)d_in[4];
    const float* Wq   = (const float*)d_in[5];
    const float* Wv   = (const float*)d_in[6];
    float* out = (float*)d_out;
    unsigned short* ws = (unsigned short*)d_ws;  // kh|qh|vh bf16, 6.3 MB

    // WL scratch lives in d_out (384 KB of 4 MB); attn fully overwrites out.
    unsigned short* WL = (unsigned short*)d_out;

    dim3 wb(256), wg(8, 3);
    wconv_kernel<<<wg, wb, 0, stream>>>(Wk, Wq, Wv, WL);

    dim3 pb(256), pg(Bn * Tn / 16, 3);
    proj_kernel<<<pg, pb, 0, stream>>>(k, q, v, WL, ws);

    dim3 ab(128), ag(512);
    attn_kernel<<<ag, ab, 0, stream>>>(ws, mask, out);
}

// Round 9
// 256.381 us; speedup vs baseline: 1.0880x; 1.0880x over previous
//
#include <hip/hip_runtime.h>
#include <hip/hip_bf16.h>
#include <math.h>

#define Bn 8
#define Tn 2048
#define Cn 1024
#define Hn 64
#define BTHb ((size_t)Bn * Tn * Hn)   // elements per projected matrix (bf16)
#define WLU  8192                     // 16B W-fragment units per matrix
#define WLS  ((size_t)WLU * 8)        // shorts per matrix (128 KB)

typedef __attribute__((ext_vector_type(8))) short bf16x8;
typedef __attribute__((ext_vector_type(4))) float f32x4;

static __device__ __forceinline__ unsigned short bf16rne(float f) {
    union { float f; unsigned u; } x; x.f = f;
    return (unsigned short)((x.u + 0x7FFFu + ((x.u >> 16) & 1u)) >> 16);
}

// HW round-to-nearest-even f32->bf16 (pairs into v_cvt_pk_bf16_f32)
static __device__ __forceinline__ unsigned short hwbf16(float f) {
    union { __hip_bfloat16 h; unsigned short u; } c;
    c.h = __float2bfloat16(f);
    return c.u;
}

static __device__ __forceinline__ bf16x8 cvt8(const float4 a, const float4 b) {
    bf16x8 r;
    r[0] = (short)hwbf16(a.x); r[1] = (short)hwbf16(a.y);
    r[2] = (short)hwbf16(a.z); r[3] = (short)hwbf16(a.w);
    r[4] = (short)hwbf16(b.x); r[5] = (short)hwbf16(b.y);
    r[6] = (short)hwbf16(b.z); r[7] = (short)hwbf16(b.w);
    return r;
}

// ---------------------------------------------------------------------------
// W pre-conversion: fp32 W[h][c] -> bf16 MFMA B-fragments, fragment-ordered.
// Output parked in d_out (384 KB of 4 MB; attn fully overwrites out after).
// ---------------------------------------------------------------------------
__global__ __launch_bounds__(256) void wconv_kernel(
    const float* __restrict__ Wk, const float* __restrict__ Wq,
    const float* __restrict__ Wv, unsigned short* __restrict__ WL)
{
    const int which = blockIdx.y;
    const float* W = (which == 0) ? Wk : (which == 1) ? Wq : Wv;
    unsigned short* dst = WL + (size_t)which * WLS;
    const int tid = threadIdx.x;
#pragma unroll
    for (int i = 0; i < 4; ++i) {
        const int u    = blockIdx.x * 1024 + i * 256 + tid;
        const int kc32 = u >> 8;
        const int ht   = (u >> 6) & 3;
        const int l    = u & 63;
        const float* wp =
            W + (size_t)(ht * 16 + (l & 15)) * Cn + kc32 * 32 + (l >> 4) * 8;
        const float4 a = *(const float4*)wp;
        const float4 b = *(const float4*)(wp + 4);
        *(bf16x8*)&dst[(size_t)u * 8] = cvt8(a, b);
    }
}

// ---------------------------------------------------------------------------
// MFMA projection v10: v8 structure + NONTEMPORAL X reads. Across v1-v8,
// FETCH_SIZE was pinned at ~100MB of 192MB input (47% L3-served) and
// delivered BW at ~2.3 TB/s no matter the structure. Theory: streaming X
// through L3 (miss+allocate+evict every iteration) caps the delivered
// path; X is single-use and should never allocate. NT loads ('nt' bit)
// bypass cache allocation. W fragments (WL) stay cached -- truly reused.
// Falsifier: if FETCH_SIZE/hbm_gbps/dur don't move, proj is at a
// delivered-BW ceiling and gets frozen.
// ---------------------------------------------------------------------------
__global__ __launch_bounds__(256, 4) void proj_kernel(
    const float* __restrict__ k, const float* __restrict__ q,
    const float* __restrict__ v,
    const unsigned short* __restrict__ WL,
    unsigned short* __restrict__ ws)
{
    const int which = blockIdx.y;
    const float* X = (which == 0) ? k : (which == 1) ? q : v;
    const unsigned short* WLm = WL + (size_t)which * WLS;
    unsigned short* O = ws + (size_t)which * BTHb;

    __shared__ __align__(16) float smem[8192];          // 32 KB
    unsigned short* Xbf = (unsigned short*)smem;        // [16][1024] swizzled

    const int tid  = threadIdx.x;
    const int wave = __builtin_amdgcn_readfirstlane(tid >> 6);  // K-quarter
    const int lane = tid & 63;
    const int m    = lane & 15;
    const int quad = lane >> 4;
    const int row0 = blockIdx.x * 16;

    const float* Xt = X + (size_t)row0 * Cn + tid * 4;
#pragma unroll
    for (int p = 0; p < 16; ++p) {
        const f32x4 xv = __builtin_nontemporal_load(
            (const f32x4*)(Xt + (size_t)p * Cn));
        ushort4 xb;
        xb.x = hwbf16(xv[0]); xb.y = hwbf16(xv[1]);
        xb.z = hwbf16(xv[2]); xb.w = hwbf16(xv[3]);
        const int pu = (tid >> 1) ^ (p & 7);   // 16B-unit XOR swizzle
        *(ushort4*)&Xbf[p * 1024 + pu * 8 + (tid & 1) * 4] = xb;
    }
    __syncthreads();

    f32x4 acc[4];
#pragma unroll
    for (int t = 0; t < 4; ++t) acc[t] = (f32x4){0.f, 0.f, 0.f, 0.f};

#pragma unroll
    for (int cc = 0; cc < 8; ++cc) {
        const int c  = wave * 8 + cc;
        const int pu = (c * 4 + quad) ^ (m & 7);
        const bf16x8 a = *(const bf16x8*)&Xbf[m * 1024 + pu * 8];
#pragma unroll
        for (int ht = 0; ht < 4; ++ht) {
            const bf16x8 bfr =
                *(const bf16x8*)&WLm[(size_t)((c * 4 + ht) * 64 + lane) * 8];
            acc[ht] = __builtin_amdgcn_mfma_f32_16x16x32_bf16(
                a, bfr, acc[ht], 0, 0, 0);
        }
    }

    __syncthreads();   // everyone done reading Xbf
    float (*Rs)[64][17] = (float (*)[64][17])smem;      // 13 KB < 32 KB
    if (wave > 0) {
#pragma unroll
        for (int ht = 0; ht < 4; ++ht)
#pragma unroll
            for (int r = 0; r < 4; ++r)
                Rs[wave - 1][lane][ht * 4 + r] = acc[ht][r];
    }
    __syncthreads();
    if (wave == 0) {
#pragma unroll
        for (int w = 0; w < 3; ++w)
#pragma unroll
            for (int ht = 0; ht < 4; ++ht)
#pragma unroll
                for (int r = 0; r < 4; ++r)
                    acc[ht][r] += Rs[w][lane][ht * 4 + r];

#pragma unroll
        for (int ht = 0; ht < 4; ++ht)
#pragma unroll
            for (int r = 0; r < 4; ++r)
                O[(size_t)(row0 + quad * 4 + r) * Hn + ht * 16 + m] =
                    bf16rne(acc[ht][r]);
    }
}

// ---------------------------------------------------------------------------
// MFMA flash attention v10: KVBLK = 128 (serial chain 32 -> 16).
// v9 (row-split, deep-first) was NULL -- but it held the per-block key-tile
// chain at 32, so chain length is the untested lever. Per 128-key tile:
// stage K[128][64] + V^T[64][128] bf16, QK^T = 8 col-tiles x 2 kc, online
// softmax over 8 col-tiles, PV = 4 kc x 4 dim-tiles. Barriers and prefetch
// latency exposure per key halve. grid (32,8) x 256 thr; LDS 54 KB.
// ---------------------------------------------------------------------------
__global__ __launch_bounds__(256) void attn_kernel(
    const unsigned short* __restrict__ ws,
    const int* __restrict__ mask,
    float* __restrict__ out)
{
    const unsigned short* kh = ws;
    const unsigned short* qh = ws + BTHb;
    const unsigned short* vh = ws + 2 * BTHb;

    const int b   = blockIdx.y;
    const int qt  = blockIdx.x;
    const int tid = threadIdx.x;
    const int wave = __builtin_amdgcn_readfirstlane(tid >> 6);
    const int lane = tid & 63;
    const int ln   = lane & 15;
    const int quad = lane >> 4;

    __shared__ unsigned short Ks[128][72];   // [kpos][dim]
    __shared__ unsigned short Vt[64][136];   // [dim][kpos]
    __shared__ unsigned short Ps[64][136];   // [q-row local][kpos]
    __shared__ int Msk[128];

    const int ntile = (qt + 2) >> 1;        // 128-key tiles for this block
    const int wrb = qt * 64 + wave * 16;    // wave's first q-row

    // Q A-frags: A[m=ln][k=quad*8+j], 2 chunks of K=32
    bf16x8 qa[2];
#pragma unroll
    for (int kc = 0; kc < 2; ++kc)
        qa[kc] = *(const bf16x8*)(qh + ((size_t)b * Tn + wrb + ln) * Hn
                                     + kc * 32 + quad * 8);

    f32x4 oacc[4];
#pragma unroll
    for (int t = 0; t < 4; ++t) oacc[t] = (f32x4){0.f, 0.f, 0.f, 0.f};
    float mrow[4] = {-1e30f, -1e30f, -1e30f, -1e30f};
    float lrow[4] = {0.f, 0.f, 0.f, 0.f};

    // staging (256 thr): K row=tid>>1 (128 rows), half-dim seg=tid&1 (64B);
    //                    V key=tid&127, dims (tid>>7)*32..+32 (transpose)
    const int krow = tid >> 1, kseg = tid & 1;
    const int vcol = tid & 127, vseg = tid >> 7;

    uint4 kreg[4], vreg[4];
    int mreg = 0;
    {
        const unsigned short* kp =
            kh + ((size_t)b * Tn + krow) * Hn + kseg * 32;
        kreg[0] = *(const uint4*)kp;
        kreg[1] = *(const uint4*)(kp + 8);
        kreg[2] = *(const uint4*)(kp + 16);
        kreg[3] = *(const uint4*)(kp + 24);
        const unsigned short* vp =
            vh + ((size_t)b * Tn + vcol) * Hn + vseg * 32;
        vreg[0] = *(const uint4*)vp;
        vreg[1] = *(const uint4*)(vp + 8);
        vreg[2] = *(const uint4*)(vp + 16);
        vreg[3] = *(const uint4*)(vp + 24);
        if (tid < 128) mreg = mask[(size_t)b * Tn + tid];
    }

    for (int jj = 0; jj < ntile; ++jj) {
        __syncthreads();   // previous tile's LDS readers done
        *(uint4*)&Ks[krow][kseg * 32]      = kreg[0];
        *(uint4*)&Ks[krow][kseg * 32 + 8]  = kreg[1];
        *(uint4*)&Ks[krow][kseg * 32 + 16] = kreg[2];
        *(uint4*)&Ks[krow][kseg * 32 + 24] = kreg[3];
        {
            const unsigned short* vs = (const unsigned short*)vreg;
#pragma unroll
            for (int dd = 0; dd < 32; ++dd)
                Vt[vseg * 32 + dd][vcol] = vs[dd];
        }
        if (tid < 128) Msk[tid] = mreg;
        __syncthreads();   // staged tile visible

        if (jj + 1 < ntile) {   // prefetch next tile; overlaps compute
            const unsigned short* kp = kh +
                ((size_t)b * Tn + (jj + 1) * 128 + krow) * Hn + kseg * 32;
            kreg[0] = *(const uint4*)kp;
            kreg[1] = *(const uint4*)(kp + 8);
            kreg[2] = *(const uint4*)(kp + 16);
            kreg[3] = *(const uint4*)(kp + 24);
            const unsigned short* vp = vh +
                ((size_t)b * Tn + (jj + 1) * 128 + vcol) * Hn + vseg * 32;
            vreg[0] = *(const uint4*)vp;
            vreg[1] = *(const uint4*)(vp + 8);
            vreg[2] = *(const uint4*)(vp + 16);
            vreg[3] = *(const uint4*)(vp + 24);
            if (tid < 128) mreg = mask[(size_t)b * Tn + (jj + 1) * 128 + tid];
        }

        // ---- S = Q K^T : 8 col-tiles (16 kpos each) x 2 K-chunks ----
        f32x4 sacc[8];
#pragma unroll
        for (int t = 0; t < 8; ++t) sacc[t] = (f32x4){0.f, 0.f, 0.f, 0.f};
#pragma unroll
        for (int kc = 0; kc < 2; ++kc) {
#pragma unroll
            for (int nt = 0; nt < 8; ++nt) {
                const bf16x8 kb =
                    *(const bf16x8*)&Ks[nt * 16 + ln][kc * 32 + quad * 8];
                sacc[nt] = __builtin_amdgcn_mfma_f32_16x16x32_bf16(
                    qa[kc], kb, sacc[nt], 0, 0, 0);
            }
        }

        // ---- online softmax in C-layout (rows quad*4+r, col nt*16+ln) ----
        const bool fullv = (2 * (jj + 1) <= qt);   // tile fully causal-valid
        float pv[8][4];
        float mt[4] = {-1e30f, -1e30f, -1e30f, -1e30f};
#pragma unroll
        for (int nt = 0; nt < 8; ++nt) {
            const bool mk = (Msk[nt * 16 + ln] != 0);
            const int kpos = jj * 128 + nt * 16 + ln;
#pragma unroll
            for (int r = 0; r < 4; ++r) {
                float s = sacc[nt][r] * 0.125f;
                const bool valid =
                    mk && (fullv || kpos <= wrb + quad * 4 + r);
                s = valid ? s : -1e30f;
                pv[nt][r] = s;
                mt[r] = fmaxf(mt[r], s);
            }
        }
#pragma unroll
        for (int r = 0; r < 4; ++r) {
            mt[r] = fmaxf(mt[r], __shfl_xor(mt[r], 1));
            mt[r] = fmaxf(mt[r], __shfl_xor(mt[r], 2));
            mt[r] = fmaxf(mt[r], __shfl_xor(mt[r], 4));
            mt[r] = fmaxf(mt[r], __shfl_xor(mt[r], 8));
        }
        float alpha[4], rsum[4];
#pragma unroll
        for (int r = 0; r < 4; ++r) {
            const float mn = fmaxf(mrow[r], mt[r]);
            alpha[r] = __expf(mrow[r] - mn);
            mrow[r] = mn;
            rsum[r] = 0.f;
        }
#pragma unroll
        for (int nt = 0; nt < 8; ++nt)
#pragma unroll
            for (int r = 0; r < 4; ++r) {
                const float p = (pv[nt][r] <= -1e29f)
                                    ? 0.f
                                    : __expf(pv[nt][r] - mrow[r]);
                pv[nt][r] = p;
                rsum[r] += p;
            }
#pragma unroll
        for (int r = 0; r < 4; ++r) {
            rsum[r] += __shfl_xor(rsum[r], 1);
            rsum[r] += __shfl_xor(rsum[r], 2);
            rsum[r] += __shfl_xor(rsum[r], 4);
            rsum[r] += __shfl_xor(rsum[r], 8);
            lrow[r] = lrow[r] * alpha[r] + rsum[r];
        }
#pragma unroll
        for (int nt = 0; nt < 4; ++nt)
#pragma unroll
            for (int r = 0; r < 4; ++r) oacc[nt][r] *= alpha[r];

        // ---- P -> LDS (bf16), wave-private region ----
#pragma unroll
        for (int nt = 0; nt < 8; ++nt)
#pragma unroll
            for (int r = 0; r < 4; ++r)
                Ps[wave * 16 + quad * 4 + r][nt * 16 + ln] =
                    bf16rne(pv[nt][r]);
        // wave-private LDS round-trip: drain DS writes, keep vmcnt in flight
        asm volatile("s_waitcnt lgkmcnt(0)" ::: "memory");

        // ---- O += P V : A=P[m=ln][k 128], B=V^T[n=dim][k 128] ----
#pragma unroll
        for (int kc = 0; kc < 4; ++kc) {
            const bf16x8 pa =
                *(const bf16x8*)&Ps[wave * 16 + ln][kc * 32 + quad * 8];
#pragma unroll
            for (int nt = 0; nt < 4; ++nt) {
                const bf16x8 vb =
                    *(const bf16x8*)&Vt[nt * 16 + ln][kc * 32 + quad * 8];
                oacc[nt] = __builtin_amdgcn_mfma_f32_16x16x32_bf16(
                    pa, vb, oacc[nt], 0, 0, 0);
            }
        }
    }

    // ---- epilogue: divide by l, fp32 store ----
#pragma unroll
    for (int r = 0; r < 4; ++r) {
        const float inv = 1.0f / lrow[r];
        const size_t rowoff = ((size_t)b * Tn + wrb + quad * 4 + r) * Hn;
#pragma unroll
        for (int nt = 0; nt < 4; ++nt)
            out[rowoff + nt * 16 + ln] = oacc[nt][r] * inv;
    }
}

extern "C" void kernel_launch(void* const* d_in, const int* in_sizes, int n_in,
                              void* d_out, int out_size, void* d_ws, size_t ws_size,
                              hipStream_t stream)
{
    const float* k    = (const float*)d_in[0];
    const float* q    = (const float*)d_in[1];
    const float* v    = (const float*)d_in[2];
    const int*   mask = (const int*)d_in[3];
    const float* Wk   = (const float*)d_in[4];
    const float* Wq   = (const float*)d_in[5];
    const float* Wv   = (const float*)d_in[6];
    float* out = (float*)d_out;
    unsigned short* ws = (unsigned short*)d_ws;  // kh|qh|vh bf16, 6.3 MB

    // WL scratch lives in d_out (384 KB of 4 MB); attn fully overwrites out.
    unsigned short* WL = (unsigned short*)d_out;

    dim3 wb(256), wg(8, 3);
    wconv_kernel<<<wg, wb, 0, stream>>>(Wk, Wq, Wv, WL);

    dim3 pb(256), pg(Bn * Tn / 16, 3);
    proj_kernel<<<pg, pb, 0, stream>>>(k, q, v, WL, ws);

    dim3 ab(256), ag(Tn / 64, Bn);
    attn_kernel<<<ag, ab, 0, stream>>>(ws, mask, out);
}